// Round 7
// baseline (623.617 us; speedup 1.0000x reference)
//
#include <hip/hip_runtime.h>

#define B_  2
#define S_  2048
#define D_  512
#define H_  8
#define E_  512
#define HE_ 4096

typedef _Float16 half8_t  __attribute__((ext_vector_type(8)));
typedef _Float16 half4_t  __attribute__((ext_vector_type(4)));
typedef float    floatx4  __attribute__((ext_vector_type(4)));
typedef __attribute__((address_space(1))) const unsigned int* gas_ptr;
typedef __attribute__((address_space(3))) unsigned int*       las_ptr;

// ---------------- fused cast fp32 -> fp16 for q,k,v (vectorized) ----------------
__global__ __launch_bounds__(256) void cast3_f16_kernel(
    const float* __restrict__ s0, const float* __restrict__ s1, const float* __restrict__ s2,
    _Float16* __restrict__ d0, _Float16* __restrict__ d1, _Float16* __restrict__ d2, int n4) {
    int i = blockIdx.x * 256 + threadIdx.x;
    if (i >= n4) return;
    const float* s = (blockIdx.y == 0) ? s0 : (blockIdx.y == 1) ? s1 : s2;
    _Float16*    d = (blockIdx.y == 0) ? d0 : (blockIdx.y == 1) ? d1 : d2;
    float4 v = ((const float4*)s)[i];
    half4_t h = { (_Float16)v.x, (_Float16)v.y, (_Float16)v.z, (_Float16)v.w };
    ((half4_t*)d)[i] = h;
}

// ------------- transpose + cast: 3 sources selected by z (Wq/Wk/Wv), each [H][R][C] ------
__global__ __launch_bounds__(256) void transpose3_cast_kernel(
    const float* __restrict__ p0, const float* __restrict__ p1, const float* __restrict__ p2,
    _Float16* __restrict__ q0, _Float16* __restrict__ q1, _Float16* __restrict__ q2,
    int R, int C) {
    __shared__ float t[32][33];
    int which = blockIdx.z >> 3, hh = blockIdx.z & 7;
    const float* src = ((which == 0) ? p0 : (which == 1) ? p1 : p2) + (long long)hh * R * C;
    _Float16*    dst = ((which == 0) ? q0 : (which == 1) ? q1 : q2) + (long long)hh * R * C;
    int c0 = blockIdx.x * 32, r0 = blockIdx.y * 32;
    int tx = threadIdx.x, ty = threadIdx.y;
#pragma unroll
    for (int i = 0; i < 32; i += 8)
        t[ty + i][tx] = src[(long long)(r0 + ty + i) * C + (c0 + tx)];
    __syncthreads();
#pragma unroll
    for (int i = 0; i < 32; i += 8)
        dst[(long long)(c0 + ty + i) * R + (r0 + tx)] = (_Float16)t[tx][ty + i];
}

// ------------- plain transpose + cast: src fp32 [R,C] -> dst fp16 [C,R] -------------
__global__ __launch_bounds__(256) void transpose_cast_kernel(const float* __restrict__ src,
                                                             _Float16* __restrict__ dst,
                                                             int R, int C) {
    __shared__ float t[32][33];
    int c0 = blockIdx.x * 32, r0 = blockIdx.y * 32;
    int tx = threadIdx.x, ty = threadIdx.y;
#pragma unroll
    for (int i = 0; i < 32; i += 8)
        t[ty + i][tx] = src[(long long)(r0 + ty + i) * C + (c0 + tx)];
    __syncthreads();
#pragma unroll
    for (int i = 0; i < 32; i += 8)
        dst[(long long)(c0 + ty + i) * R + (r0 + tx)] = (_Float16)t[tx][ty + i];
}

// ------------- bt-GEMM, double-buffered: C[M,N] = A[M,K]*Bt[N,K]^T (+bias[n]) -------------
// 128x128 tile, 4 waves 2x2, wave = 64x64 via 4x4 mfma_f32_16x16x32_f16.
// Explicit LDS dbuf, BK=32: each iter issues NEXT tile's global_load_lds into the
// other buffer right after the barrier, so the barrier's vmcnt(0) drain waits on
// loads that are a full compute-phase old (we run at <2 blocks/CU — implicit
// wave overlap does NOT cover the drain here, unlike m99/m100's regime).
__global__ __launch_bounds__(256) void gemm_bt_kernel(
    const _Float16* __restrict__ A, const _Float16* __restrict__ Bt,
    const float* __restrict__ bias, void* __restrict__ C, int out_f32,
    int K, int lda, int ldb,
    long long a_b, long long a_h, long long b_b, long long b_h,
    long long c_b, long long c_h, int c_rs, int c_cs,
    int divh, int bias_h)
{
    int z  = blockIdx.z;
    int bb = z / divh, hh = z % divh;
    A  += bb * a_b + hh * a_h;
    Bt += bb * b_b + hh * b_h;
    long long coff = bb * c_b + hh * c_h;

    int m0 = blockIdx.y * 128;
    int n0 = blockIdx.x * 128;

    __shared__ __align__(16) _Float16 As[2][128][32];   // 2 x 8 KB
    __shared__ __align__(16) _Float16 Bs[2][128][32];   // 2 x 8 KB

    int tid  = threadIdx.x;
    int wave = tid >> 6, lane = tid & 63;
    int quad = lane >> 4, l16 = lane & 15;
    int wy = (wave >> 1) * 64, wx = (wave & 1) * 64;

    // staging: wave w rows [w*16 + j*64), lane covers (row = lane>>2, col = (lane&3)*8)
    int srow = (wave << 4) + (lane >> 2);
    int scol = (lane & 3) * 8;

    floatx4 acc[4][4] = {};

    // prologue: stage k0=0 into buffer 0
    {
        const _Float16* gA = A + (long long)(m0 + srow) * lda + scol;
        const _Float16* gB = Bt + (long long)(n0 + srow) * ldb + scol;
        _Float16* lA = &As[0][0][0] + (wave << 9);
        _Float16* lB = &Bs[0][0][0] + (wave << 9);
#pragma unroll
        for (int j = 0; j < 2; j++) {
            __builtin_amdgcn_global_load_lds((gas_ptr)(gA + (long long)(j << 6) * lda),
                                             (las_ptr)(lA + (j << 11)), 16, 0, 0);
            __builtin_amdgcn_global_load_lds((gas_ptr)(gB + (long long)(j << 6) * ldb),
                                             (las_ptr)(lB + (j << 11)), 16, 0, 0);
        }
    }

    int nk = K >> 5;
    for (int ki = 0; ki < nk; ki++) {
        int cur = ki & 1;
        __syncthreads();   // drains: loads for buf[cur], issued one full iter ago

        if (ki + 1 < nk) {   // prefetch next tile into the other buffer
            int k1 = (ki + 1) << 5;
            const _Float16* gA = A + (long long)(m0 + srow) * lda + k1 + scol;
            const _Float16* gB = Bt + (long long)(n0 + srow) * ldb + k1 + scol;
            _Float16* lA = &As[cur ^ 1][0][0] + (wave << 9);
            _Float16* lB = &Bs[cur ^ 1][0][0] + (wave << 9);
#pragma unroll
            for (int j = 0; j < 2; j++) {
                __builtin_amdgcn_global_load_lds((gas_ptr)(gA + (long long)(j << 6) * lda),
                                                 (las_ptr)(lA + (j << 11)), 16, 0, 0);
                __builtin_amdgcn_global_load_lds((gas_ptr)(gB + (long long)(j << 6) * ldb),
                                                 (las_ptr)(lB + (j << 11)), 16, 0, 0);
            }
        }

        half8_t af[4], bf[4];
#pragma unroll
        for (int i = 0; i < 4; i++) {
            af[i] = *(const half8_t*)&As[cur][wy + i * 16 + l16][quad * 8];
            bf[i] = *(const half8_t*)&Bs[cur][wx + i * 16 + l16][quad * 8];
        }
#pragma unroll
        for (int mi = 0; mi < 4; mi++)
#pragma unroll
            for (int ni = 0; ni < 4; ni++)
                acc[mi][ni] = __builtin_amdgcn_mfma_f32_16x16x32_f16(af[mi], bf[ni], acc[mi][ni], 0, 0, 0);
    }

    float*    fC = (float*)C;
    _Float16* hC = (_Float16*)C;
#pragma unroll
    for (int mi = 0; mi < 4; mi++)
#pragma unroll
        for (int ni = 0; ni < 4; ni++)
#pragma unroll
            for (int r = 0; r < 4; r++) {
                int row = m0 + wy + mi * 16 + quad * 4 + r;
                int col = n0 + wx + ni * 16 + l16;
                float v = acc[mi][ni][r];
                if (bias) v += bias[hh * bias_h + col];
                long long addr = coff + (long long)row * c_rs + (long long)col * c_cs;
                if (out_f32) fC[addr] = v; else hC[addr] = (_Float16)v;
            }
}

// ------------- masked softmax, 8 heads per block (mask row reused via L1) -------------
__global__ __launch_bounds__(512) void softmax_mask8_kernel(_Float16* __restrict__ sc,
                                                            const int* __restrict__ mask)
{
    int b = blockIdx.z, s = blockIdx.x;
    int wave = threadIdx.x >> 6, lane = threadIdx.x & 63;
    _Float16* row = sc + ((long long)(b * H_ + wave) * S_ + s) * S_;
    const int* mrow = mask + ((long long)b * S_ + s) * S_;

    half8_t h[4];
    float v[32];
    float mx = -3.0e38f;
#pragma unroll
    for (int j = 0; j < 4; j++) {
        int c = j * 512 + lane * 8;
        h[j] = *(const half8_t*)(row + c);
        int4 mA = *(const int4*)(mrow + c);
        int4 mB = *(const int4*)(mrow + c + 4);
        int mm[8] = { mA.x, mA.y, mA.z, mA.w, mB.x, mB.y, mB.z, mB.w };
#pragma unroll
        for (int e = 0; e < 8; e++) {
            float val = mm[e] ? (float)h[j][e] : -1.0e9f;
            v[j * 8 + e] = val;
            mx = fmaxf(mx, val);
        }
    }
#pragma unroll
    for (int o = 32; o > 0; o >>= 1) mx = fmaxf(mx, __shfl_xor(mx, o));

    float sum = 0.0f;
#pragma unroll
    for (int i = 0; i < 32; i++) { v[i] = __expf(v[i] - mx); sum += v[i]; }
#pragma unroll
    for (int o = 32; o > 0; o >>= 1) sum += __shfl_xor(sum, o);

    float inv = 1.0f / sum;
#pragma unroll
    for (int j = 0; j < 4; j++) {
#pragma unroll
        for (int e = 0; e < 8; e++) h[j][e] = (_Float16)(v[j * 8 + e] * inv);
        *(half8_t*)(row + j * 512 + lane * 8) = h[j];
    }
}

// ------------- split-K bt-GEMM, 128(M)x64(N) tile, dbuf, fp32 atomic accumulate ----------
__global__ __launch_bounds__(256) void gemm_bt_n64_splitk_kernel(
    const _Float16* __restrict__ A, const _Float16* __restrict__ Bt,
    const float* __restrict__ bias, float* __restrict__ C,
    int K, int lda, int ldb, int ldc, int ksplit)
{
    int m0 = blockIdx.y * 128;
    int n0 = blockIdx.x * 64;
    int kchunk = K / ksplit;
    int kbeg = blockIdx.z * kchunk;

    __shared__ __align__(16) _Float16 As[2][128][32];
    __shared__ __align__(16) _Float16 Bs[2][64][32];

    int tid  = threadIdx.x;
    int wave = tid >> 6, lane = tid & 63;
    int quad = lane >> 4, l16 = lane & 15;
    int wy = (wave >> 1) * 64, wx = (wave & 1) * 32;

    int srow = (wave << 4) + (lane >> 2);
    int scol = (lane & 3) * 8;

    floatx4 acc[4][2] = {};

    {
        const _Float16* gA = A + (long long)(m0 + srow) * lda + kbeg + scol;
        const _Float16* gB = Bt + (long long)(n0 + srow) * ldb + kbeg + scol;
        _Float16* lA = &As[0][0][0] + (wave << 9);
        _Float16* lB = &Bs[0][0][0] + (wave << 9);
#pragma unroll
        for (int j = 0; j < 2; j++)
            __builtin_amdgcn_global_load_lds((gas_ptr)(gA + (long long)(j << 6) * lda),
                                             (las_ptr)(lA + (j << 11)), 16, 0, 0);
        __builtin_amdgcn_global_load_lds((gas_ptr)gB, (las_ptr)lB, 16, 0, 0);
    }

    int nk = kchunk >> 5;
    for (int ki = 0; ki < nk; ki++) {
        int cur = ki & 1;
        __syncthreads();

        if (ki + 1 < nk) {
            int k1 = kbeg + ((ki + 1) << 5);
            const _Float16* gA = A + (long long)(m0 + srow) * lda + k1 + scol;
            const _Float16* gB = Bt + (long long)(n0 + srow) * ldb + k1 + scol;
            _Float16* lA = &As[cur ^ 1][0][0] + (wave << 9);
            _Float16* lB = &Bs[cur ^ 1][0][0] + (wave << 9);
#pragma unroll
            for (int j = 0; j < 2; j++)
                __builtin_amdgcn_global_load_lds((gas_ptr)(gA + (long long)(j << 6) * lda),
                                                 (las_ptr)(lA + (j << 11)), 16, 0, 0);
            __builtin_amdgcn_global_load_lds((gas_ptr)gB, (las_ptr)lB, 16, 0, 0);
        }

        half8_t af[4], bf[2];
#pragma unroll
        for (int i = 0; i < 4; i++)
            af[i] = *(const half8_t*)&As[cur][wy + i * 16 + l16][quad * 8];
#pragma unroll
        for (int i = 0; i < 2; i++)
            bf[i] = *(const half8_t*)&Bs[cur][wx + i * 16 + l16][quad * 8];
#pragma unroll
        for (int mi = 0; mi < 4; mi++)
#pragma unroll
            for (int ni = 0; ni < 2; ni++)
                acc[mi][ni] = __builtin_amdgcn_mfma_f32_16x16x32_f16(af[mi], bf[ni], acc[mi][ni], 0, 0, 0);
    }

    int addb = (blockIdx.z == 0) && bias;
#pragma unroll
    for (int mi = 0; mi < 4; mi++)
#pragma unroll
        for (int ni = 0; ni < 2; ni++)
#pragma unroll
            for (int r = 0; r < 4; r++) {
                int row = m0 + wy + mi * 16 + quad * 4 + r;
                int col = n0 + wx + ni * 16 + l16;
                float v = acc[mi][ni][r];
                if (addb) v += bias[col];
                atomicAdd(&C[(long long)row * ldc + col], v);
            }
}

extern "C" void kernel_launch(void* const* d_in, const int* in_sizes, int n_in,
                              void* d_out, int out_size, void* d_ws, size_t ws_size,
                              hipStream_t stream)
{
    const float* qin = (const float*)d_in[0];
    const float* kin = (const float*)d_in[1];
    const float* vin = (const float*)d_in[2];
    const int*   mask = (const int*)d_in[3];
    const float* Wq = (const float*)d_in[4];
    const float* bq = (const float*)d_in[5];
    const float* Wk = (const float*)d_in[6];
    const float* bk = (const float*)d_in[7];
    const float* Wv = (const float*)d_in[8];
    const float* bv = (const float*)d_in[9];
    const float* Wo = (const float*)d_in[10];
    const float* bo = (const float*)d_in[11];
    float* out = (float*)d_out;

    char* ws = (char*)d_ws;
    size_t off = 0;
    _Float16* WoT = (_Float16*)(ws + off); off += (size_t)E_ * HE_ * 2;           // 4 MiB
    _Float16* Qb  = (_Float16*)(ws + off); off += (size_t)B_ * H_ * S_ * E_ * 2;  // 32 MiB
    _Float16* Kb  = (_Float16*)(ws + off); off += (size_t)B_ * H_ * S_ * E_ * 2;  // 32 MiB
    _Float16* VT  = (_Float16*)(ws + off); off += (size_t)B_ * H_ * E_ * S_ * 2;  // 32 MiB
    size_t region = off;
    _Float16* Xq  = (_Float16*)(ws + region);
    _Float16* Xk  = Xq  + (size_t)B_ * S_ * D_;
    _Float16* Xv  = Xk  + (size_t)B_ * S_ * D_;
    _Float16* WqT = Xv  + (size_t)B_ * S_ * D_;
    _Float16* WkT = WqT + (size_t)H_ * E_ * D_;
    _Float16* WvT = WkT + (size_t)H_ * E_ * D_;
    _Float16* SC  = (_Float16*)(ws + region);   // fp16 scores -> normalized P (in place)
    _Float16* cat = Qb;                          // aliases Q (dead after scores GEMM)

    long long SE = (long long)S_ * E_;
    long long SS = (long long)S_ * S_;
    long long ES = (long long)E_ * S_;
    long long SD = (long long)S_ * D_;
    long long ED = (long long)E_ * D_;

    auto gemm = [&](const _Float16* A, const _Float16* Bt, const float* bias,
                    void* C, int f32, int M, int N, int K, int lda, int ldb,
                    long long ab, long long ah, long long bb2, long long bh,
                    long long cb, long long ch, int rs, int cs,
                    int divh, int biash, int nz) {
        gemm_bt_kernel<<<dim3(N / 128, M / 128, nz), 256, 0, stream>>>(
            A, Bt, bias, C, f32, K, lda, ldb, ab, ah, bb2, bh, cb, ch, rs, cs, divh, biash);
    };

    // zero d_out (split-K atomic accumulation target)
    hipMemsetAsync(d_out, 0, (size_t)out_size * sizeof(float), stream);

    // 1) cast q,k,v to fp16 (one fused launch)
    int n4 = B_ * S_ * D_ / 4;
    cast3_f16_kernel<<<dim3(n4 / 256, 3), 256, 0, stream>>>(qin, kin, vin, Xq, Xk, Xv, n4);

    // 2) transpose+cast weights to Bt form (QKV batched; Wo separate)
    dim3 tb(32, 8);
    transpose3_cast_kernel<<<dim3(E_ / 32, D_ / 32, 24), tb, 0, stream>>>(
        Wq, Wk, Wv, WqT, WkT, WvT, D_, E_);
    transpose_cast_kernel<<<dim3(E_ / 32, HE_ / 32, 1), tb, 0, stream>>>(Wo, WoT, HE_, E_);

    // 3) projections: Q,K -> [B,H,S,E]; V -> VT [B,H,E,S] via strided epilogue store
    gemm(Xq, WqT, bq, Qb, 0, S_, E_, D_, D_, D_,
         SD, 0, 0, ED, (long long)H_ * SE, SE, E_, 1, H_, E_, B_ * H_);
    gemm(Xk, WkT, bk, Kb, 0, S_, E_, D_, D_, D_,
         SD, 0, 0, ED, (long long)H_ * SE, SE, E_, 1, H_, E_, B_ * H_);
    gemm(Xv, WvT, bv, VT, 0, S_, E_, D_, D_, D_,
         SD, 0, 0, ED, (long long)H_ * ES, ES, 1, S_, H_, E_, B_ * H_);

    // 4a) raw scores (unmasked; mask handled in softmax)
    gemm(Qb, Kb, nullptr, SC, 0, S_, S_, E_, E_, E_,
         0, SE, 0, SE, 0, SS, S_, 1, B_ * H_ * 2 /*divh>z: bb=0,hh=z*/, 0, B_ * H_);

    // 4b) masked softmax in place, 8 heads per block
    softmax_mask8_kernel<<<dim3(S_, 1, B_), 512, 0, stream>>>(SC, mask);

    // 4c) P @ V -> cat[b,s,h*E+e]
    gemm(SC, VT, nullptr, cat, 0, S_, E_, S_, S_, S_,
         (long long)H_ * SS, SS, (long long)H_ * ES, ES,
         (long long)S_ * HE_, E_, HE_, 1, H_, 0, B_ * H_);

    // 5) output projection: split-K (4) 128x64-tile GEMM, atomic fp32 accumulate
    gemm_bt_n64_splitk_kernel<<<dim3(E_ / 64, (B_ * S_) / 128, 4), 256, 0, stream>>>(
        cat, WoT, bo, out, HE_, HE_, HE_, E_, 4);
}